// Round 2
// baseline (719.007 us; speedup 1.0000x reference)
//
#include <hip/hip_runtime.h>
#include <hip/hip_bf16.h>
#include <math.h>

#define B_    64
#define S_    2048
#define DIN_  512
#define H_    1024
#define SPLIT_ 32                 // s-splits per batch row
#define ROWS_  (S_ / SPLIT_)      // 64 s-rows per block
#define RPW_   (ROWS_ / 4)        // 16 s-rows per wave

__device__ __forceinline__ float fast_tanh(float x) {
    // tanh(x) = 1 - 2/(e^{2x}+1); |x| < ~12 here, no overflow concerns
    float e = __expf(2.0f * x);
    return 1.0f - 2.0f * __builtin_amdgcn_rcpf(e + 1.0f);
}

// -------- Kernel 0: detect mask storage (int32 vs 1-byte bool) ---------------
// Reads only the first 131072 bytes = valid under BOTH layouts.
// If any int32 view value is not 0/1, storage must be 1-byte bools.
__global__ __launch_bounds__(256)
void detect_mask(const unsigned int* __restrict__ m, int* __restrict__ flag)
{
    int bad = 0;
    for (int i = threadIdx.x; i < 32768; i += 256)
        bad |= (m[i] > 1u) ? 1 : 0;
    __shared__ int sh[256];
    sh[threadIdx.x] = bad;
    __syncthreads();
    if (threadIdx.x == 0) {
        int r = 0;
        #pragma unroll 8
        for (int i = 0; i < 256; ++i) r |= sh[i];
        flag[0] = r;      // 1 => byte mode (bool), 0 => int32 mode
    }
}

// ---------------- Kernel A: x = inp @ W + b  ([B,DIN]@[DIN,H]) ----------------
__global__ __launch_bounds__(256)
void linear_x(const float* __restrict__ inp, const float* __restrict__ W,
              const float* __restrict__ bias, float* __restrict__ x)
{
    const int idx = blockIdx.x * 256 + threadIdx.x;   // grid = B*H/256
    const int b = idx >> 10;
    const int h = idx & (H_ - 1);
    const float* ip = inp + b * DIN_;
    float acc = bias[h];
    #pragma unroll 8
    for (int k = 0; k < DIN_; ++k)
        acc += ip[k] * W[k * H_ + h];
    x[idx] = acc;
}

// ------------- Kernel B: fused scores + online-softmax weighted sum -----------
__global__ __launch_bounds__(256)
void attn_pass1(const float* __restrict__ ctx,
                const void* __restrict__ mask_raw,
                const int* __restrict__ mask_flag,
                const float* __restrict__ xvec,
                const float* __restrict__ vvec,
                float* __restrict__ scores,
                float* __restrict__ part_ml,
                float* __restrict__ part_acc)
{
    const int blk  = blockIdx.x;          // b * SPLIT + sp
    const int b    = blk >> 5;
    const int sp   = blk & (SPLIT_ - 1);
    const int tid  = threadIdx.x;
    const int wave = tid >> 6;
    const int lane = tid & 63;

    const bool bytemode = (mask_flag[0] != 0);
    const unsigned char* mask_b = (const unsigned char*)mask_raw;
    const int*           mask_i = (const int*)mask_raw;

    // lane-owned h indices: h = j*256 + 4*lane + {0..3}, j = 0..3  (16 h's/lane)
    float4 xv[4], vv[4], acc[4];
    #pragma unroll
    for (int j = 0; j < 4; ++j) {
        const int h = j * 256 + lane * 4;
        xv[j]  = *(const float4*)(xvec + b * H_ + h);
        vv[j]  = *(const float4*)(vvec + h);
        acc[j] = make_float4(0.f, 0.f, 0.f, 0.f);
    }
    float m = -INFINITY, l = 0.f;

    const float* cb     = ctx + (size_t)b * S_ * H_;
    const int    s_base = sp * ROWS_ + wave;

    for (int r = 0; r < RPW_; ++r) {
        const int s = s_base + r * 4;               // wave-uniform
        const int mi = b * S_ + s;
        const bool msk = bytemode ? (mask_b[mi] != 0) : (mask_i[mi] != 0);
        if (!msk) {
            const float* crow = cb + (size_t)s * H_;
            float4 c[4];
            #pragma unroll
            for (int j = 0; j < 4; ++j)
                c[j] = *(const float4*)(crow + j * 256 + lane * 4);
            float p = 0.f;
            #pragma unroll
            for (int j = 0; j < 4; ++j) {
                p += vv[j].x * fast_tanh(xv[j].x + c[j].x);
                p += vv[j].y * fast_tanh(xv[j].y + c[j].y);
                p += vv[j].z * fast_tanh(xv[j].z + c[j].z);
                p += vv[j].w * fast_tanh(xv[j].w + c[j].w);
            }
            #pragma unroll
            for (int off = 32; off > 0; off >>= 1)
                p += __shfl_xor(p, off);
            const float score = p;
            if (lane == 0) scores[mi] = score;
            if (score > m) {                         // rescale on new max
                const float f = __expf(m - score);   // exp(-inf)=0 on first hit
                l *= f;
                #pragma unroll
                for (int j = 0; j < 4; ++j) {
                    acc[j].x *= f; acc[j].y *= f; acc[j].z *= f; acc[j].w *= f;
                }
                m = score;
            }
            const float w = __expf(score - m);
            l += w;
            #pragma unroll
            for (int j = 0; j < 4; ++j) {
                acc[j].x += w * c[j].x; acc[j].y += w * c[j].y;
                acc[j].z += w * c[j].z; acc[j].w += w * c[j].w;
            }
        } else {
            if (lane == 0) scores[mi] = -INFINITY;
        }
    }

    // merge the 4 waves' (m, l, acc) through LDS
    __shared__ float sm[4], sl[4];
    __shared__ float sacc[4][H_];
    #pragma unroll
    for (int j = 0; j < 4; ++j)
        *(float4*)(&sacc[wave][j * 256 + lane * 4]) = acc[j];
    if (lane == 0) { sm[wave] = m; sl[wave] = l; }
    __syncthreads();

    const float mb = fmaxf(fmaxf(sm[0], sm[1]), fmaxf(sm[2], sm[3]));
    float fw[4]; float lb = 0.f;
    #pragma unroll
    for (int w = 0; w < 4; ++w) {
        fw[w] = (sm[w] == -INFINITY) ? 0.f : __expf(sm[w] - mb);
        lb += fw[w] * sl[w];
    }
    float* pa = part_acc + (size_t)blk * H_;
    for (int h = tid; h < H_; h += 256)
        pa[h] = fw[0]*sacc[0][h] + fw[1]*sacc[1][h]
              + fw[2]*sacc[2][h] + fw[3]*sacc[3][h];
    if (tid == 0) { part_ml[blk * 2] = mb; part_ml[blk * 2 + 1] = lb; }
}

// --------- Kernel C: combine split partials, emit both outputs ---------------
__global__ __launch_bounds__(256)
void finalize(const float* __restrict__ part_ml,
              const float* __restrict__ part_acc,
              const float* __restrict__ scores,
              float* __restrict__ out_applied,
              float* __restrict__ out_weights)
{
    const int b   = blockIdx.x;
    const int tid = threadIdx.x;
    __shared__ float smp[SPLIT_], slp[SPLIT_], sf[SPLIT_];
    if (tid < SPLIT_) {
        smp[tid] = part_ml[(b * SPLIT_ + tid) * 2];
        slp[tid] = part_ml[(b * SPLIT_ + tid) * 2 + 1];
    }
    __syncthreads();
    float mg = -INFINITY;
    for (int p = 0; p < SPLIT_; ++p) mg = fmaxf(mg, smp[p]);
    if (tid < SPLIT_)
        sf[tid] = (smp[tid] == -INFINITY) ? 0.f : __expf(smp[tid] - mg);
    __syncthreads();
    float lg = 0.f;
    for (int p = 0; p < SPLIT_; ++p) lg += sf[p] * slp[p];
    const float inv_l = 1.0f / lg;

    for (int h = tid; h < H_; h += 256) {
        float a = 0.f;
        for (int p = 0; p < SPLIT_; ++p)
            a += sf[p] * part_acc[(size_t)(b * SPLIT_ + p) * H_ + h];
        out_applied[b * H_ + h] = a * inv_l;
    }
    for (int s = tid; s < S_; s += 256)
        out_weights[b * S_ + s] = __expf(scores[b * S_ + s] - mg) * inv_l;
}

extern "C" void kernel_launch(void* const* d_in, const int* in_sizes, int n_in,
                              void* d_out, int out_size, void* d_ws, size_t ws_size,
                              hipStream_t stream)
{
    const float* inp  = (const float*)d_in[0];
    // d_in[1] = hidden : unused by the reference
    const float* ctx  = (const float*)d_in[2];
    const void*  mask = d_in[3];                     // dtype detected on device
    const float* W    = (const float*)d_in[4];
    const float* bias = (const float*)d_in[5];
    const float* v    = (const float*)d_in[6];

    float* out_applied = (float*)d_out;              // [B,1,H]  = 65536 f32
    float* out_weights = (float*)d_out + B_ * H_;    // [B,1,S]  = 131072 f32

    float* ws       = (float*)d_ws;
    float* x        = ws;                            // B*H        = 65536
    float* scores   = x + B_ * H_;                   // B*S        = 131072
    float* part_ml  = scores + B_ * S_;              // B*SPLIT*2  = 4096
    float* part_acc = part_ml + B_ * SPLIT_ * 2;     // B*SPLIT*H  = 2097152
    int*   mflag    = (int*)(part_acc + (size_t)B_ * SPLIT_ * H_);
    // total ws use: ~9.2 MB

    detect_mask<<<1, 256, 0, stream>>>((const unsigned int*)mask, mflag);
    linear_x <<<B_ * H_ / 256, 256, 0, stream>>>(inp, W, bias, x);
    attn_pass1<<<B_ * SPLIT_,  256, 0, stream>>>(ctx, mask, mflag, x, v,
                                                 scores, part_ml, part_acc);
    finalize <<<B_,            256, 0, stream>>>(part_ml, part_acc, scores,
                                                 out_applied, out_weights);
}

// Round 3
// 683.810 us; speedup vs baseline: 1.0515x; 1.0515x over previous
//
#include <hip/hip_runtime.h>
#include <hip/hip_bf16.h>
#include <math.h>

#define B_    64
#define S_    2048
#define DIN_  512
#define H_    1024
#define SPLIT_ 32                 // s-splits per batch row
#define ROWS_  (S_ / SPLIT_)      // 64 s-rows per block
#define RPW_   (ROWS_ / 4)        // 16 s-rows per wave

__device__ __forceinline__ float fast_tanh(float x) {
    // tanh(x) = 1 - 2/(e^{2x}+1); |x| < ~12 here, no overflow concerns
    float e = __expf(2.0f * x);
    return 1.0f - 2.0f * __builtin_amdgcn_rcpf(e + 1.0f);
}

// ------- Kernel A: x = inp @ W + b, plus block 256 detects mask dtype --------
// detect: reads first 131072 bytes of mask (valid under both layouts, since
// mask has 131072 elements of >=1 byte). Any int32-view value not in {0,1}
// implies 1-byte bool storage (random 0/1 bytes packed as int32 are >1 with
// probability 1 - 2^-24 per element).
__global__ __launch_bounds__(256)
void linear_x(const float* __restrict__ inp, const float* __restrict__ W,
              const float* __restrict__ bias, float* __restrict__ x,
              const unsigned int* __restrict__ mask_u32, int* __restrict__ mflag)
{
    if (blockIdx.x == B_ * H_ / 256) {           // detection block
        int bad = 0;
        for (int i = threadIdx.x; i < 32768; i += 256)
            bad |= (mask_u32[i] > 1u) ? 1 : 0;
        __shared__ int sh[256];
        sh[threadIdx.x] = bad;
        __syncthreads();
        if (threadIdx.x == 0) {
            int r = 0;
            #pragma unroll 8
            for (int i = 0; i < 256; ++i) r |= sh[i];
            mflag[0] = r;                        // 1 => byte mode, 0 => int32
        }
        return;
    }
    const int idx = blockIdx.x * 256 + threadIdx.x;   // B*H threads
    const int b = idx >> 10;
    const int h = idx & (H_ - 1);
    const float* ip = inp + b * DIN_;
    float acc = bias[h];
    #pragma unroll 8
    for (int k = 0; k < DIN_; ++k)
        acc += ip[k] * W[k * H_ + h];
    x[idx] = acc;
}

// ------------- Kernel B: fused scores + online-softmax weighted sum -----------
__global__ __launch_bounds__(256)
void attn_pass1(const float* __restrict__ ctx,
                const void* __restrict__ mask_raw,
                const int* __restrict__ mask_flag,
                const float* __restrict__ xvec,
                const float* __restrict__ vvec,
                float* __restrict__ scores,
                float* __restrict__ part_ml,
                float* __restrict__ part_acc)
{
    const int blk  = blockIdx.x;          // b * SPLIT + sp
    const int b    = blk >> 5;
    const int sp   = blk & (SPLIT_ - 1);
    const int tid  = threadIdx.x;
    const int wave = tid >> 6;
    const int lane = tid & 63;

    const bool bytemode = (mask_flag[0] != 0);
    const unsigned char* mask_b = (const unsigned char*)mask_raw;
    const int*           mask_i = (const int*)mask_raw;

    // lane-owned h indices: h = j*256 + 4*lane + {0..3}, j = 0..3  (16 h's/lane)
    float4 xv[4], vv[4], acc[4];
    #pragma unroll
    for (int j = 0; j < 4; ++j) {
        const int h = j * 256 + lane * 4;
        xv[j]  = *(const float4*)(xvec + b * H_ + h);
        vv[j]  = *(const float4*)(vvec + h);
        acc[j] = make_float4(0.f, 0.f, 0.f, 0.f);
    }
    float m = -INFINITY, l = 0.f;

    const float* cb     = ctx + (size_t)b * S_ * H_;
    const int    s_base = sp * ROWS_ + wave;

    for (int r = 0; r < RPW_; ++r) {
        const int s = s_base + r * 4;               // wave-uniform
        const int mi = b * S_ + s;
        const bool msk = bytemode ? (mask_b[mi] != 0) : (mask_i[mi] != 0);
        if (!msk) {
            const float* crow = cb + (size_t)s * H_;
            float4 c[4];
            #pragma unroll
            for (int j = 0; j < 4; ++j)
                c[j] = *(const float4*)(crow + j * 256 + lane * 4);
            float p = 0.f;
            #pragma unroll
            for (int j = 0; j < 4; ++j) {
                p += vv[j].x * fast_tanh(xv[j].x + c[j].x);
                p += vv[j].y * fast_tanh(xv[j].y + c[j].y);
                p += vv[j].z * fast_tanh(xv[j].z + c[j].z);
                p += vv[j].w * fast_tanh(xv[j].w + c[j].w);
            }
            #pragma unroll
            for (int off = 32; off > 0; off >>= 1)
                p += __shfl_xor(p, off);
            const float score = p;
            if (lane == 0) scores[mi] = score;
            if (score > m) {                         // rescale on new max
                const float f = __expf(m - score);   // exp(-inf)=0 on first hit
                l *= f;
                #pragma unroll
                for (int j = 0; j < 4; ++j) {
                    acc[j].x *= f; acc[j].y *= f; acc[j].z *= f; acc[j].w *= f;
                }
                m = score;
            }
            const float w = __expf(score - m);
            l += w;
            #pragma unroll
            for (int j = 0; j < 4; ++j) {
                acc[j].x += w * c[j].x; acc[j].y += w * c[j].y;
                acc[j].z += w * c[j].z; acc[j].w += w * c[j].w;
            }
        } else {
            if (lane == 0) scores[mi] = -INFINITY;
        }
    }

    // merge the 4 waves' (m, l, acc) through LDS
    __shared__ float sm[4], sl[4];
    __shared__ float sacc[4][H_];
    #pragma unroll
    for (int j = 0; j < 4; ++j)
        *(float4*)(&sacc[wave][j * 256 + lane * 4]) = acc[j];
    if (lane == 0) { sm[wave] = m; sl[wave] = l; }
    __syncthreads();

    const float mb = fmaxf(fmaxf(sm[0], sm[1]), fmaxf(sm[2], sm[3]));
    float fw[4]; float lb = 0.f;
    #pragma unroll
    for (int w = 0; w < 4; ++w) {
        fw[w] = (sm[w] == -INFINITY) ? 0.f : __expf(sm[w] - mb);
        lb += fw[w] * sl[w];
    }
    // one float4 per thread: 256 threads * 4 = 1024 = H_
    {
        float4 r  = make_float4(0.f, 0.f, 0.f, 0.f);
        #pragma unroll
        for (int w = 0; w < 4; ++w) {
            const float4 t = *(const float4*)(&sacc[w][tid * 4]);
            r.x += fw[w] * t.x; r.y += fw[w] * t.y;
            r.z += fw[w] * t.z; r.w += fw[w] * t.w;
        }
        ((float4*)(part_acc + (size_t)blk * H_))[tid] = r;
    }
    if (tid == 0) { part_ml[blk * 2] = mb; part_ml[blk * 2 + 1] = lb; }
}

// --------- Kernel C: combine split partials, emit both outputs ---------------
__global__ __launch_bounds__(256)
void finalize(const float* __restrict__ part_ml,
              const float* __restrict__ part_acc,
              const float* __restrict__ scores,
              float* __restrict__ out_applied,
              float* __restrict__ out_weights)
{
    const int b   = blockIdx.x;
    const int tid = threadIdx.x;
    __shared__ float smp[SPLIT_], slp[SPLIT_], sf[SPLIT_];
    if (tid < SPLIT_) {
        smp[tid] = part_ml[(b * SPLIT_ + tid) * 2];
        slp[tid] = part_ml[(b * SPLIT_ + tid) * 2 + 1];
    }
    __syncthreads();
    float mg = -INFINITY;
    #pragma unroll
    for (int p = 0; p < SPLIT_; ++p) mg = fmaxf(mg, smp[p]);
    if (tid < SPLIT_)
        sf[tid] = (smp[tid] == -INFINITY) ? 0.f : __expf(smp[tid] - mg);
    __syncthreads();
    float lg = 0.f;
    #pragma unroll
    for (int p = 0; p < SPLIT_; ++p) lg += sf[p] * slp[p];
    const float inv_l = 1.0f / lg;

    // one float4 per thread over h (256*4 = 1024)
    {
        const float4* pa4 = (const float4*)(part_acc + (size_t)b * SPLIT_ * H_);
        float4 a = make_float4(0.f, 0.f, 0.f, 0.f);
        #pragma unroll 8
        for (int p = 0; p < SPLIT_; ++p) {
            const float  f = sf[p];
            const float4 t = pa4[p * (H_ / 4) + tid];
            a.x += f * t.x; a.y += f * t.y; a.z += f * t.z; a.w += f * t.w;
        }
        a.x *= inv_l; a.y *= inv_l; a.z *= inv_l; a.w *= inv_l;
        ((float4*)(out_applied + b * H_))[tid] = a;
    }
    #pragma unroll
    for (int k = 0; k < S_ / 256; ++k) {
        const int s = k * 256 + tid;
        out_weights[b * S_ + s] = __expf(scores[b * S_ + s] - mg) * inv_l;
    }
}

extern "C" void kernel_launch(void* const* d_in, const int* in_sizes, int n_in,
                              void* d_out, int out_size, void* d_ws, size_t ws_size,
                              hipStream_t stream)
{
    const float* inp  = (const float*)d_in[0];
    // d_in[1] = hidden : unused by the reference
    const float* ctx  = (const float*)d_in[2];
    const void*  mask = d_in[3];                     // dtype detected on device
    const float* W    = (const float*)d_in[4];
    const float* bias = (const float*)d_in[5];
    const float* v    = (const float*)d_in[6];

    float* out_applied = (float*)d_out;              // [B,1,H]  = 65536 f32
    float* out_weights = (float*)d_out + B_ * H_;    // [B,1,S]  = 131072 f32

    float* ws       = (float*)d_ws;
    float* x        = ws;                            // B*H        = 65536
    float* scores   = x + B_ * H_;                   // B*S        = 131072
    float* part_ml  = scores + B_ * S_;              // B*SPLIT*2  = 4096
    float* part_acc = part_ml + B_ * SPLIT_ * 2;     // B*SPLIT*H  = 2097152
    int*   mflag    = (int*)(part_acc + (size_t)B_ * SPLIT_ * H_);
    // total ws use: ~9.2 MB

    linear_x  <<<B_ * H_ / 256 + 1, 256, 0, stream>>>(inp, W, bias, x,
                                                      (const unsigned int*)mask, mflag);
    attn_pass1<<<B_ * SPLIT_,       256, 0, stream>>>(ctx, mask, mflag, x, v,
                                                      scores, part_ml, part_acc);
    finalize  <<<B_,                256, 0, stream>>>(part_ml, part_acc, scores,
                                                      out_applied, out_weights);
}